// Round 1
// baseline (139.617 us; speedup 1.0000x reference)
//
#include <hip/hip_runtime.h>
#include <string.h>

#define NB 16
#define NC 256
#define NH 56
#define NW 56
#define NHW (NH * NW)          // 3136
#define NK 256
#define NSORT 4096

// ---- sortable-float helpers -------------------------------------------------
__device__ inline unsigned int flip_f32(float f) {
    unsigned int u = __float_as_uint(f);
    return (u & 0x80000000u) ? ~u : (u | 0x80000000u);
}
__device__ inline float unflip_f32(unsigned int u) {
    u = (u & 0x80000000u) ? (u ^ 0x80000000u) : ~u;
    return __uint_as_float(u);
}

// ---- kernel 1: per-pixel L2 norm over channels ------------------------------
__global__ void norm_kernel(const float* __restrict__ f, float* __restrict__ nrm) {
    int pix = blockIdx.x * blockDim.x + threadIdx.x;
    if (pix >= NB * NHW) return;
    int b = pix / NHW;
    int hw = pix - b * NHW;
    const float* p = f + (size_t)b * NC * NHW + hw;
    float acc = 0.f;
#pragma unroll 8
    for (int c = 0; c < NC; ++c) {
        float v = p[(size_t)c * NHW];
        acc += v * v;
    }
    nrm[pix] = sqrtf(acc);
}

// ---- kernel 2: similarity map ----------------------------------------------
__global__ void sim_kernel(const float* __restrict__ f, const float* __restrict__ nrm,
                           float* __restrict__ sim) {
    int pix = blockIdx.x * blockDim.x + threadIdx.x;
    if (pix >= NB * NHW) return;
    int b = pix / NHW;
    int hw = pix - b * NHW;
    int y = hw / NW;
    int x = hw - y * NW;
    int xl = (x > 0) ? x - 1 : 0;
    int xr = (x < NW - 1) ? x + 1 : NW - 1;
    int yu = (y < NH - 1) ? y + 1 : NH - 1;   // 'top' shift  -> f[y+1]
    int yd = (y > 0) ? y - 1 : 0;             // 'bot' shift  -> f[y-1]
    int hl = y * NW + xl, hr = y * NW + xr;
    int hu = yu * NW + x, hd = yd * NW + x;

    const float* base = f + (size_t)b * NC * NHW;
    float hdot = 0.f, vdot = 0.f;
#pragma unroll 4
    for (int c = 0; c < NC; ++c) {
        size_t off = (size_t)c * NHW;
        hdot += base[off + hl] * base[off + hr];
        vdot += base[off + hu] * base[off + hd];
    }
    const float* nb = nrm + b * NHW;
    float s = 0.5f * (hdot / (nb[hl] * nb[hr]) + vdot / (nb[hu] * nb[hd]));
    sim[pix] = s;
}

// ---- kernel 3: per-batch top-K via bitonic sort of packed keys --------------
// key = flip(val)<<32 | (0xFFFFFFFF - idx)  -> descending sort gives
// descending values, ties broken by LOWER idx first (== jax.lax.top_k).
__global__ void __launch_bounds__(1024)
topk_kernel(const float* __restrict__ sim, int* __restrict__ idx_out,
            float* __restrict__ vals_out, float* __restrict__ y_out,
            float* __restrict__ x_out) {
    __shared__ unsigned long long keys[NSORT];
    const int b = blockIdx.x;
    const int tid = threadIdx.x;
    const float* s = sim + (size_t)b * NHW;

    for (int i = tid; i < NSORT; i += blockDim.x) {
        if (i < NHW) {
            unsigned long long k = ((unsigned long long)flip_f32(s[i]) << 32) |
                                   (unsigned long long)(0xFFFFFFFFu - (unsigned int)i);
            keys[i] = k;
        } else {
            keys[i] = 0ull;   // smallest possible -> never selected
        }
    }
    __syncthreads();

    for (int k = 2; k <= NSORT; k <<= 1) {
        for (int j = k >> 1; j > 0; j >>= 1) {
            for (int i = tid; i < NSORT; i += blockDim.x) {
                int ixj = i ^ j;
                if (ixj > i) {
                    unsigned long long a = keys[i], c = keys[ixj];
                    // overall DESCENDING sort
                    bool swap = ((i & k) == 0) ? (a < c) : (a > c);
                    if (swap) { keys[i] = c; keys[ixj] = a; }
                }
            }
            __syncthreads();
        }
    }

    if (tid < NK) {
        unsigned long long k = keys[tid];
        unsigned int lo = (unsigned int)(k & 0xFFFFFFFFull);
        int idx = (int)(0xFFFFFFFFu - lo);
        float val = unflip_f32((unsigned int)(k >> 32));
        int o = b * NK + tid;
        idx_out[o] = idx;
        vals_out[o] = val;
        y_out[o] = (float)(idx / NW);
        x_out[o] = (float)(idx % NW);
    }
}

// ---- kernel 4: gather point features [B,K,C] --------------------------------
__global__ void gather_kernel(const float* __restrict__ f, const int* __restrict__ idx,
                              float* __restrict__ out) {
    int blk = blockIdx.x;          // b*NK + k
    int b = blk >> 8;              // NK == 256
    int p = idx[blk];
    out[(size_t)blk * NC + threadIdx.x] =
        f[(size_t)b * NC * NHW + (size_t)threadIdx.x * NHW + (size_t)p];
}

extern "C" void kernel_launch(void* const* d_in, const int* in_sizes, int n_in,
                              void* d_out, int out_size, void* d_ws, size_t ws_size,
                              hipStream_t stream) {
    const float* f = (const float*)d_in[0];

    // output layout: point_feat [B,K,C] | vals [B,K] | ycoord [B,K] | xcoord [B,K]
    float* out_feat = (float*)d_out;
    float* out_vals = out_feat + (size_t)NB * NK * NC;
    float* out_y    = out_vals + (size_t)NB * NK;
    float* out_x    = out_y    + (size_t)NB * NK;

    // workspace layout: nrm [B*HW] f32 | sim [B*HW] f32 | idx [B*K] i32
    float* nrm = (float*)d_ws;
    float* sim = nrm + (size_t)NB * NHW;
    int*   idx = (int*)(sim + (size_t)NB * NHW);

    const int npix = NB * NHW;
    const int blk = 256;
    norm_kernel<<<(npix + blk - 1) / blk, blk, 0, stream>>>(f, nrm);
    sim_kernel<<<(npix + blk - 1) / blk, blk, 0, stream>>>(f, nrm, sim);
    topk_kernel<<<NB, 1024, 0, stream>>>(sim, idx, out_vals, out_y, out_x);
    gather_kernel<<<NB * NK, NC, 0, stream>>>(f, idx, out_feat);
}

// Round 2
// 93.446 us; speedup vs baseline: 1.4941x; 1.4941x over previous
//
#include <hip/hip_runtime.h>

#define NB 16
#define NC 256
#define NH 56
#define NW 56
#define NHW (NH * NW)          // 3136
#define NK 256
#define TK_THREADS 512
#define CAP 1024

// ---- sortable-float helpers -------------------------------------------------
__device__ inline unsigned int flip_f32(float f) {
    unsigned int u = __float_as_uint(f);
    return (u & 0x80000000u) ? ~u : (u | 0x80000000u);
}
__device__ inline float unflip_f32(unsigned int u) {
    u = (u & 0x80000000u) ? (u ^ 0x80000000u) : ~u;
    return __uint_as_float(u);
}

// ---- kernel 1: fused norm+similarity map ------------------------------------
// sim(y,x) = 0.5*( <f[y,x-1],f[y,x+1]>/(||f[y,x-1]||*||f[y,x+1]||)
//               +  <f[y+1,x],f[y-1,x]>/(||f[y+1,x]||*||f[y-1,x]||) )
// (replicate-clamped). Norms of the 4 neighbors are accumulated from the very
// same loads the dot products need -> no separate norm pass.
// FP order kept identical to the round-1 bitwise-exact version:
//   per-accumulator sequential c-ascending sums, sqrtf(s)*sqrtf(s) denominators.
__global__ void sim_fused_kernel(const float* __restrict__ f, float* __restrict__ sim) {
    // 896 blocks (= NB*NH rows), one wave per row; XCD-chunked swizzle (896%8==0)
    int bid = blockIdx.x;
    int row = (bid & 7) * (NB * NH / 8) + (bid >> 3);
    int x = threadIdx.x;
    if (x >= NW) return;
    int b = row / NH, y = row - b * NH;

    int xl = (x > 0) ? x - 1 : 0;
    int xr = (x < NW - 1) ? x + 1 : NW - 1;
    int yu = (y < NH - 1) ? y + 1 : NH - 1;   // 'top' shift
    int yd = (y > 0) ? y - 1 : 0;             // 'bot' shift

    const float* base = f + (size_t)b * NC * NHW;
    const float* pl = base + y * NW + xl;
    const float* pr = base + y * NW + xr;
    const float* pu = base + yu * NW + x;
    const float* pd = base + yd * NW + x;

    float sl = 0.f, sr = 0.f, su = 0.f, sd = 0.f, hdot = 0.f, vdot = 0.f;
#pragma unroll 4
    for (int c = 0; c < NC; ++c) {
        size_t off = (size_t)c * NHW;
        float vl = pl[off], vr = pr[off], vu = pu[off], vdn = pd[off];
        sl += vl * vl; sr += vr * vr;
        su += vu * vu; sd += vdn * vdn;
        hdot += vl * vr; vdot += vu * vdn;
    }
    float s = 0.5f * (hdot / (sqrtf(sl) * sqrtf(sr)) + vdot / (sqrtf(su) * sqrtf(sd)));
    sim[(size_t)row * NW + x] = s;
}

// ---- kernel 2: per-batch top-K: radix-select + small bitonic sort -----------
// key = flip(val)<<32 | (0xFFFFFFFF - idx): descending sort == descending value,
// ties -> lower idx first (matches jax.lax.top_k).
__global__ void __launch_bounds__(TK_THREADS)
topk_kernel(const float* __restrict__ sim, int* __restrict__ idx_out,
            float* __restrict__ vals_out, float* __restrict__ y_out,
            float* __restrict__ x_out) {
    __shared__ unsigned int svals[NHW];          // flipped values
    __shared__ unsigned int hist[256];
    __shared__ unsigned long long cand[CAP];
    __shared__ unsigned int sh_prefix, sh_mask;
    __shared__ int sh_cnt, sh_above, sh_setS, sh_done;

    const int b = blockIdx.x;
    const int tid = threadIdx.x;
    const float* s = sim + (size_t)b * NHW;

    for (int i = tid; i < NHW; i += TK_THREADS) svals[i] = flip_f32(s[i]);
    if (tid == 0) { sh_prefix = 0u; sh_mask = 0u; sh_above = 0; sh_done = 0; }

    // progressive 8-bit radix-select: find exact threshold prefix T such that
    // 256 <= #{v >= T} <= 512 (or full 32-bit refinement on pathological ties)
    int shift = 24;
    for (int stage = 0; stage < 4; ++stage) {
        __syncthreads();
        if (sh_done) break;
        for (int i = tid; i < 256; i += TK_THREADS) hist[i] = 0u;
        __syncthreads();
        unsigned int pfx = sh_prefix, msk = sh_mask;
        for (int i = tid; i < NHW; i += TK_THREADS) {
            unsigned int v = svals[i];
            if ((v & msk) == pfx) atomicAdd(&hist[(v >> shift) & 255u], 1u);
        }
        __syncthreads();
        if (tid == 0) {
            int kneed = NK - sh_above;
            int cum = 0, c = 255;
            for (; c > 0; --c) {
                int h = (int)hist[c];
                if (cum + h >= kneed) break;
                cum += h;
            }
            sh_above += cum;
            sh_setS = (int)hist[c];
            sh_prefix = pfx | ((unsigned int)c << shift);
            sh_mask = msk | (255u << shift);
            if (sh_above + sh_setS <= 512 || shift == 0) sh_done = 1;
        }
        shift -= 8;
    }
    __syncthreads();

    // compact candidates: v >= T  (count = sh_above + sh_setS >= NK by construction)
    if (tid == 0) sh_cnt = 0;
    __syncthreads();
    unsigned int T = sh_prefix;
    for (int i = tid; i < NHW; i += TK_THREADS) {
        unsigned int v = svals[i];
        if (v >= T) {
            int pos = atomicAdd(&sh_cnt, 1);
            if (pos < CAP)
                cand[pos] = ((unsigned long long)v << 32) |
                            (unsigned long long)(0xFFFFFFFFu - (unsigned int)i);
        }
    }
    __syncthreads();
    int nc = sh_cnt; if (nc > CAP) nc = CAP;
    const int NS = (nc <= 512) ? 512 : CAP;
    for (int i = tid; i < NS; i += TK_THREADS) if (i >= nc) cand[i] = 0ull;
    __syncthreads();

    // bitonic sort NS keys descending
    for (int k = 2; k <= NS; k <<= 1) {
        for (int j = k >> 1; j > 0; j >>= 1) {
            for (int i = tid; i < NS; i += TK_THREADS) {
                int ixj = i ^ j;
                if (ixj > i) {
                    unsigned long long a = cand[i], c2 = cand[ixj];
                    bool sw = ((i & k) == 0) ? (a < c2) : (a > c2);
                    if (sw) { cand[i] = c2; cand[ixj] = a; }
                }
            }
            __syncthreads();
        }
    }

    if (tid < NK) {
        unsigned long long kk = cand[tid];
        unsigned int lo = (unsigned int)(kk & 0xFFFFFFFFull);
        int idx = (int)(0xFFFFFFFFu - lo);
        float val = unflip_f32((unsigned int)(kk >> 32));
        int o = b * NK + tid;
        idx_out[o] = idx;
        vals_out[o] = val;
        y_out[o] = (float)(idx / NW);
        x_out[o] = (float)(idx % NW);
    }
}

// ---- kernel 3: gather point features [B,K,C] --------------------------------
__global__ void gather_kernel(const float* __restrict__ f, const int* __restrict__ idx,
                              float* __restrict__ out) {
    int blk = blockIdx.x;          // b*NK + k
    int b = blk >> 8;              // NK == 256
    int p = idx[blk];
    out[(size_t)blk * NC + threadIdx.x] =
        f[(size_t)b * NC * NHW + (size_t)threadIdx.x * NHW + (size_t)p];
}

extern "C" void kernel_launch(void* const* d_in, const int* in_sizes, int n_in,
                              void* d_out, int out_size, void* d_ws, size_t ws_size,
                              hipStream_t stream) {
    const float* f = (const float*)d_in[0];

    // output layout: point_feat [B,K,C] | vals [B,K] | ycoord [B,K] | xcoord [B,K]
    float* out_feat = (float*)d_out;
    float* out_vals = out_feat + (size_t)NB * NK * NC;
    float* out_y    = out_vals + (size_t)NB * NK;
    float* out_x    = out_y    + (size_t)NB * NK;

    // workspace: sim [B*HW] f32 | idx [B*K] i32
    float* sim = (float*)d_ws;
    int*   idx = (int*)(sim + (size_t)NB * NHW);

    sim_fused_kernel<<<NB * NH, 64, 0, stream>>>(f, sim);
    topk_kernel<<<NB, TK_THREADS, 0, stream>>>(sim, idx, out_vals, out_y, out_x);
    gather_kernel<<<NB * NK, NC, 0, stream>>>(f, idx, out_feat);
}

// Round 3
// 82.380 us; speedup vs baseline: 1.6948x; 1.1343x over previous
//
#include <hip/hip_runtime.h>

#define NB 16
#define NC 256
#define NH 56
#define NW 56
#define NHW (NH * NW)          // 3136
#define NK 256
#define TK_THREADS 512
#define CAP 1024

// ---- sortable-float helpers -------------------------------------------------
__device__ inline unsigned int flip_f32(float f) {
    unsigned int u = __float_as_uint(f);
    return (u & 0x80000000u) ? ~u : (u | 0x80000000u);
}
__device__ inline float unflip_f32(unsigned int u) {
    u = (u & 0x80000000u) ? (u ^ 0x80000000u) : ~u;
    return __uint_as_float(u);
}

// ---- kernel 1: fused norm+similarity map, 4 waves splitting channels --------
// sim(y,x) = 0.5*( <f[y,x-1],f[y,x+1]>/(||f[y,x-1]||*||f[y,x+1]||)
//               +  <f[y+1,x],f[y-1,x]>/(||f[y+1,x]||*||f[y-1,x]||) )
// One block per image row; wave w accumulates channels [64w,64w+64) for the
// row's 56 pixels; cross-wave reduce in LDS in fixed (w0+w1+w2+w3) order.
__global__ void __launch_bounds__(256)
sim_fused_kernel(const float* __restrict__ f, float* __restrict__ sim) {
    __shared__ float red[4][6][64];
    int bid = blockIdx.x;
    // XCD-chunked swizzle: XCD k handles contiguous row chunk [112k,112k+112)
    int row = (bid & 7) * (NB * NH / 8) + (bid >> 3);
    int x = threadIdx.x & 63;
    int wv = threadIdx.x >> 6;
    int b = row / NH, y = row - b * NH;

    float sl = 0.f, sr = 0.f, su = 0.f, sd = 0.f, hdot = 0.f, vdot = 0.f;
    if (x < NW) {
        int xl = (x > 0) ? x - 1 : 0;
        int xr = (x < NW - 1) ? x + 1 : NW - 1;
        int yu = (y < NH - 1) ? y + 1 : NH - 1;   // 'top' shift
        int yd = (y > 0) ? y - 1 : 0;             // 'bot' shift

        const float* base = f + (size_t)b * NC * NHW + (size_t)wv * 64 * NHW;
        const float* pl = base + y * NW + xl;
        const float* pr = base + y * NW + xr;
        const float* pu = base + yu * NW + x;
        const float* pd = base + yd * NW + x;

#pragma unroll 8
        for (int c = 0; c < 64; ++c) {
            size_t off = (size_t)c * NHW;
            float vl = pl[off], vr = pr[off], vu = pu[off], vdn = pd[off];
            sl += vl * vl; sr += vr * vr;
            su += vu * vu; sd += vdn * vdn;
            hdot += vl * vr; vdot += vu * vdn;
        }
    }
    red[wv][0][x] = sl; red[wv][1][x] = sr;
    red[wv][2][x] = su; red[wv][3][x] = sd;
    red[wv][4][x] = hdot; red[wv][5][x] = vdot;
    __syncthreads();

    if (threadIdx.x < NW) {   // wave 0, lanes 0..55
        float a0 = red[0][0][x] + red[1][0][x] + red[2][0][x] + red[3][0][x];
        float a1 = red[0][1][x] + red[1][1][x] + red[2][1][x] + red[3][1][x];
        float a2 = red[0][2][x] + red[1][2][x] + red[2][2][x] + red[3][2][x];
        float a3 = red[0][3][x] + red[1][3][x] + red[2][3][x] + red[3][3][x];
        float a4 = red[0][4][x] + red[1][4][x] + red[2][4][x] + red[3][4][x];
        float a5 = red[0][5][x] + red[1][5][x] + red[2][5][x] + red[3][5][x];
        float s = 0.5f * (a4 / (sqrtf(a0) * sqrtf(a1)) + a5 / (sqrtf(a2) * sqrtf(a3)));
        sim[(size_t)row * NW + x] = s;
    }
}

// ---- kernel 2: per-batch top-K: radix-select + small bitonic sort -----------
// key = flip(val)<<32 | (0xFFFFFFFF - idx): descending sort == descending value,
// ties -> lower idx first (matches jax.lax.top_k).
__global__ void __launch_bounds__(TK_THREADS)
topk_kernel(const float* __restrict__ sim, int* __restrict__ idx_out,
            float* __restrict__ vals_out, float* __restrict__ y_out,
            float* __restrict__ x_out) {
    __shared__ unsigned int svals[NHW];          // flipped values
    __shared__ unsigned int hist[256];
    __shared__ unsigned long long cand[CAP];
    __shared__ unsigned int sh_prefix, sh_mask;
    __shared__ int sh_cnt, sh_above, sh_setS, sh_done;

    const int b = blockIdx.x;
    const int tid = threadIdx.x;
    const float* s = sim + (size_t)b * NHW;

    for (int i = tid; i < NHW; i += TK_THREADS) svals[i] = flip_f32(s[i]);
    if (tid == 0) { sh_prefix = 0u; sh_mask = 0u; sh_above = 0; sh_done = 0; }

    // progressive 8-bit radix-select: find exact threshold prefix T such that
    // 256 <= #{v >= T} <= 512 (or full 32-bit refinement on pathological ties)
    int shift = 24;
    for (int stage = 0; stage < 4; ++stage) {
        __syncthreads();
        if (sh_done) break;
        for (int i = tid; i < 256; i += TK_THREADS) hist[i] = 0u;
        __syncthreads();
        unsigned int pfx = sh_prefix, msk = sh_mask;
        for (int i = tid; i < NHW; i += TK_THREADS) {
            unsigned int v = svals[i];
            if ((v & msk) == pfx) atomicAdd(&hist[(v >> shift) & 255u], 1u);
        }
        __syncthreads();
        if (tid == 0) {
            int kneed = NK - sh_above;
            int cum = 0, c = 255;
            for (; c > 0; --c) {
                int h = (int)hist[c];
                if (cum + h >= kneed) break;
                cum += h;
            }
            sh_above += cum;
            sh_setS = (int)hist[c];
            sh_prefix = pfx | ((unsigned int)c << shift);
            sh_mask = msk | (255u << shift);
            if (sh_above + sh_setS <= 512 || shift == 0) sh_done = 1;
        }
        shift -= 8;
    }
    __syncthreads();

    // compact candidates: v >= T  (count = sh_above + sh_setS >= NK by construction)
    if (tid == 0) sh_cnt = 0;
    __syncthreads();
    unsigned int T = sh_prefix;
    for (int i = tid; i < NHW; i += TK_THREADS) {
        unsigned int v = svals[i];
        if (v >= T) {
            int pos = atomicAdd(&sh_cnt, 1);
            if (pos < CAP)
                cand[pos] = ((unsigned long long)v << 32) |
                            (unsigned long long)(0xFFFFFFFFu - (unsigned int)i);
        }
    }
    __syncthreads();
    int nc = sh_cnt; if (nc > CAP) nc = CAP;
    const int NS = (nc <= 512) ? 512 : CAP;
    for (int i = tid; i < NS; i += TK_THREADS) if (i >= nc) cand[i] = 0ull;
    __syncthreads();

    // bitonic sort NS keys descending
    for (int k = 2; k <= NS; k <<= 1) {
        for (int j = k >> 1; j > 0; j >>= 1) {
            for (int i = tid; i < NS; i += TK_THREADS) {
                int ixj = i ^ j;
                if (ixj > i) {
                    unsigned long long a = cand[i], c2 = cand[ixj];
                    bool sw = ((i & k) == 0) ? (a < c2) : (a > c2);
                    if (sw) { cand[i] = c2; cand[ixj] = a; }
                }
            }
            __syncthreads();
        }
    }

    if (tid < NK) {
        unsigned long long kk = cand[tid];
        unsigned int lo = (unsigned int)(kk & 0xFFFFFFFFull);
        int idx = (int)(0xFFFFFFFFu - lo);
        float val = unflip_f32((unsigned int)(kk >> 32));
        int o = b * NK + tid;
        idx_out[o] = idx;
        vals_out[o] = val;
        y_out[o] = (float)(idx / NW);
        x_out[o] = (float)(idx % NW);
    }
}

// ---- kernel 3: gather point features [B,K,C] --------------------------------
__global__ void gather_kernel(const float* __restrict__ f, const int* __restrict__ idx,
                              float* __restrict__ out) {
    int blk = blockIdx.x;          // b*NK + k
    int b = blk >> 8;              // NK == 256
    int p = idx[blk];
    out[(size_t)blk * NC + threadIdx.x] =
        f[(size_t)b * NC * NHW + (size_t)threadIdx.x * NHW + (size_t)p];
}

extern "C" void kernel_launch(void* const* d_in, const int* in_sizes, int n_in,
                              void* d_out, int out_size, void* d_ws, size_t ws_size,
                              hipStream_t stream) {
    const float* f = (const float*)d_in[0];

    // output layout: point_feat [B,K,C] | vals [B,K] | ycoord [B,K] | xcoord [B,K]
    float* out_feat = (float*)d_out;
    float* out_vals = out_feat + (size_t)NB * NK * NC;
    float* out_y    = out_vals + (size_t)NB * NK;
    float* out_x    = out_y    + (size_t)NB * NK;

    // workspace: sim [B*HW] f32 | idx [B*K] i32
    float* sim = (float*)d_ws;
    int*   idx = (int*)(sim + (size_t)NB * NHW);

    sim_fused_kernel<<<NB * NH, 256, 0, stream>>>(f, sim);
    topk_kernel<<<NB, TK_THREADS, 0, stream>>>(sim, idx, out_vals, out_y, out_x);
    gather_kernel<<<NB * NK, NC, 0, stream>>>(f, idx, out_feat);
}

// Round 4
// 68.438 us; speedup vs baseline: 2.0400x; 1.2037x over previous
//
#include <hip/hip_runtime.h>

#define NB 16
#define NC 256
#define NH 56
#define NW 56
#define NHW (NH * NW)          // 3136
#define NK 256
#define TK_THREADS 512
#define CAP 1024

#define QPB 8                  // quads per block
#define NSL 32                 // channel slices (NC/NSL = 8 channels each)
#define CPS (NC / NSL)         // 8
#define NQUAD (NB * NH * (NW / 4))   // 12544 quads
#define P1_BLOCKS (NQUAD / QPB)      // 1568

// ---- sortable-float helpers -------------------------------------------------
__device__ inline unsigned int flip_f32(float f) {
    unsigned int u = __float_as_uint(f);
    return (u & 0x80000000u) ? ~u : (u | 0x80000000u);
}
__device__ inline float unflip_f32(unsigned int u) {
    u = (u & 0x80000000u) ? (u ^ 0x80000000u) : ~u;
    return __uint_as_float(u);
}

// ---- kernel 1: per-pixel norm2 / hprod / vprod maps -------------------------
// Thread = (quad of 4 pixels) x (8-channel slice). Per channel: 3 float4 + 2
// scalar loads; all quantities are local to the loaded data. 32 slices reduced
// in LDS in fixed ascending order.
__global__ void __launch_bounds__(256)
pass1_kernel(const float* __restrict__ f, float* __restrict__ nmap,
             float* __restrict__ hmap, float* __restrict__ vmap) {
    __shared__ float red[NSL][QPB][12];
    int bid = blockIdx.x;
    int sbid = (bid & 7) * (P1_BLOCKS / 8) + (bid >> 3);   // XCD-chunked
    int tid = threadIdx.x;
    int ql = tid & (QPB - 1);          // local quad
    int sl = tid >> 3;                 // slice 0..31
    int gq = sbid * QPB + ql;          // global quad
    int rowi = gq / 14;                // b*NH + y
    int qx = gq - rowi * 14;
    int b = rowi / NH, y = rowi - b * NH;
    int x0 = qx * 4;

    const float* base = f + (size_t)b * NC * NHW + (size_t)sl * CPS * NHW;
    int xl = (x0 > 0) ? x0 - 1 : 0;
    int xr = (x0 + 4 < NW) ? x0 + 4 : NW - 1;
    int yu = (y < NH - 1) ? y + 1 : NH - 1;
    int yd = (y > 0) ? y - 1 : 0;
    const float* pv = base + y * NW + x0;
    const float* pl = base + y * NW + xl;
    const float* pr = base + y * NW + xr;
    const float* pu = base + yu * NW + x0;
    const float* pd = base + yd * NW + x0;

    float n0 = 0.f, n1 = 0.f, n2 = 0.f, n3 = 0.f;
    float h0 = 0.f, h1 = 0.f, h2 = 0.f, h3 = 0.f;
    float w0 = 0.f, w1 = 0.f, w2 = 0.f, w3 = 0.f;
#pragma unroll 4
    for (int c = 0; c < CPS; ++c) {
        size_t off = (size_t)c * NHW;
        float4 v = *(const float4*)(pv + off);
        float  l = pl[off];
        float  r = pr[off];
        float4 u = *(const float4*)(pu + off);
        float4 d = *(const float4*)(pd + off);
        n0 += v.x * v.x; n1 += v.y * v.y; n2 += v.z * v.z; n3 += v.w * v.w;
        h0 += l   * v.y; h1 += v.x * v.z; h2 += v.y * v.w; h3 += v.z * r;
        w0 += u.x * d.x; w1 += u.y * d.y; w2 += u.z * d.z; w3 += u.w * d.w;
    }
    float* rr = red[sl][ql];
    rr[0] = n0; rr[1] = n1; rr[2]  = n2; rr[3]  = n3;
    rr[4] = h0; rr[5] = h1; rr[6]  = h2; rr[7]  = h3;
    rr[8] = w0; rr[9] = w1; rr[10] = w2; rr[11] = w3;
    __syncthreads();

    if (tid < QPB * 12) {
        int comp = tid >> 3;           // 0..11
        int qi = tid & (QPB - 1);
        float acc = 0.f;
#pragma unroll
        for (int s = 0; s < NSL; ++s) acc += red[s][qi][comp];
        int gq2 = sbid * QPB + qi;
        int rowi2 = gq2 / 14;
        int qx2 = gq2 - rowi2 * 14;
        int j = comp & 3;
        int pix = rowi2 * NW + qx2 * 4 + j;
        float* m = (comp < 4) ? nmap : (comp < 8) ? hmap : vmap;
        m[pix] = acc;
    }
}

// ---- kernel 2: fused sim-finish + per-batch top-K ---------------------------
// sim computed on the fly from nmap/hmap/vmap (nmap staged in LDS), then
// radix-select (exact threshold) + bitonic sort of <=CAP candidates.
// key = flip(val)<<32 | (0xFFFFFFFF - idx): descending sort == descending
// value, ties -> lower idx first (matches jax.lax.top_k).
__global__ void __launch_bounds__(TK_THREADS)
topk_kernel(const float* __restrict__ nmap, const float* __restrict__ hmap,
            const float* __restrict__ vmap, int* __restrict__ idx_out,
            float* __restrict__ vals_out, float* __restrict__ y_out,
            float* __restrict__ x_out) {
    __shared__ float nsh[NHW];
    __shared__ unsigned int svals[NHW];          // flipped sim values
    __shared__ unsigned int hist[256];
    __shared__ unsigned long long cand[CAP];
    __shared__ unsigned int sh_prefix, sh_mask;
    __shared__ int sh_cnt, sh_above, sh_setS, sh_done;

    const int b = blockIdx.x;
    const int tid = threadIdx.x;
    const float* nb = nmap + (size_t)b * NHW;
    const float* hb = hmap + (size_t)b * NHW;
    const float* vb = vmap + (size_t)b * NHW;

    for (int i = tid; i < NHW; i += TK_THREADS) nsh[i] = nb[i];
    if (tid == 0) { sh_prefix = 0u; sh_mask = 0u; sh_above = 0; sh_done = 0; }
    __syncthreads();

    for (int i = tid; i < NHW; i += TK_THREADS) {
        int y = i / NW, x = i - y * NW;
        int xl = (x > 0) ? x - 1 : 0;
        int xr = (x < NW - 1) ? x + 1 : NW - 1;
        int yu = (y < NH - 1) ? y + 1 : NH - 1;
        int yd = (y > 0) ? y - 1 : 0;
        float h = hb[i], v = vb[i];
        float s = 0.5f * (h / (sqrtf(nsh[y * NW + xl]) * sqrtf(nsh[y * NW + xr])) +
                          v / (sqrtf(nsh[yu * NW + x]) * sqrtf(nsh[yd * NW + x])));
        svals[i] = flip_f32(s);
    }

    // progressive 8-bit radix-select: exact threshold prefix T with
    // 256 <= #{v >= T} (and <= 512 unless full 32-bit tie refinement)
    int shift = 24;
    for (int stage = 0; stage < 4; ++stage) {
        __syncthreads();
        if (sh_done) break;
        for (int i = tid; i < 256; i += TK_THREADS) hist[i] = 0u;
        __syncthreads();
        unsigned int pfx = sh_prefix, msk = sh_mask;
        for (int i = tid; i < NHW; i += TK_THREADS) {
            unsigned int v = svals[i];
            if ((v & msk) == pfx) atomicAdd(&hist[(v >> shift) & 255u], 1u);
        }
        __syncthreads();
        if (tid == 0) {
            int kneed = NK - sh_above;
            int cum = 0, c = 255;
            for (; c > 0; --c) {
                int h = (int)hist[c];
                if (cum + h >= kneed) break;
                cum += h;
            }
            sh_above += cum;
            sh_setS = (int)hist[c];
            sh_prefix = pfx | ((unsigned int)c << shift);
            sh_mask = msk | (255u << shift);
            if (sh_above + sh_setS <= 512 || shift == 0) sh_done = 1;
        }
        shift -= 8;
    }
    __syncthreads();

    if (tid == 0) sh_cnt = 0;
    __syncthreads();
    unsigned int T = sh_prefix;
    for (int i = tid; i < NHW; i += TK_THREADS) {
        unsigned int v = svals[i];
        if (v >= T) {
            int pos = atomicAdd(&sh_cnt, 1);
            if (pos < CAP)
                cand[pos] = ((unsigned long long)v << 32) |
                            (unsigned long long)(0xFFFFFFFFu - (unsigned int)i);
        }
    }
    __syncthreads();
    int nc = sh_cnt; if (nc > CAP) nc = CAP;
    const int NS = (nc <= 512) ? 512 : CAP;
    for (int i = tid; i < NS; i += TK_THREADS) if (i >= nc) cand[i] = 0ull;
    __syncthreads();

    for (int k = 2; k <= NS; k <<= 1) {
        for (int j = k >> 1; j > 0; j >>= 1) {
            for (int i = tid; i < NS; i += TK_THREADS) {
                int ixj = i ^ j;
                if (ixj > i) {
                    unsigned long long a = cand[i], c2 = cand[ixj];
                    bool sw = ((i & k) == 0) ? (a < c2) : (a > c2);
                    if (sw) { cand[i] = c2; cand[ixj] = a; }
                }
            }
            __syncthreads();
        }
    }

    if (tid < NK) {
        unsigned long long kk = cand[tid];
        unsigned int lo = (unsigned int)(kk & 0xFFFFFFFFull);
        int idx = (int)(0xFFFFFFFFu - lo);
        float val = unflip_f32((unsigned int)(kk >> 32));
        int o = b * NK + tid;
        idx_out[o] = idx;
        vals_out[o] = val;
        y_out[o] = (float)(idx / NW);
        x_out[o] = (float)(idx % NW);
    }
}

// ---- kernel 3: gather point features [B,K,C] --------------------------------
__global__ void gather_kernel(const float* __restrict__ f, const int* __restrict__ idx,
                              float* __restrict__ out) {
    int blk = blockIdx.x;          // b*NK + k
    int b = blk >> 8;              // NK == 256
    int p = idx[blk];
    out[(size_t)blk * NC + threadIdx.x] =
        f[(size_t)b * NC * NHW + (size_t)threadIdx.x * NHW + (size_t)p];
}

extern "C" void kernel_launch(void* const* d_in, const int* in_sizes, int n_in,
                              void* d_out, int out_size, void* d_ws, size_t ws_size,
                              hipStream_t stream) {
    const float* f = (const float*)d_in[0];

    // output layout: point_feat [B,K,C] | vals [B,K] | ycoord [B,K] | xcoord [B,K]
    float* out_feat = (float*)d_out;
    float* out_vals = out_feat + (size_t)NB * NK * NC;
    float* out_y    = out_vals + (size_t)NB * NK;
    float* out_x    = out_y    + (size_t)NB * NK;

    // workspace: nmap | hmap | vmap (each B*HW f32) | idx (B*K i32)
    float* nmap = (float*)d_ws;
    float* hmap = nmap + (size_t)NB * NHW;
    float* vmap = hmap + (size_t)NB * NHW;
    int*   idx  = (int*)(vmap + (size_t)NB * NHW);

    pass1_kernel<<<P1_BLOCKS, 256, 0, stream>>>(f, nmap, hmap, vmap);
    topk_kernel<<<NB, TK_THREADS, 0, stream>>>(nmap, hmap, vmap, idx,
                                               out_vals, out_y, out_x);
    gather_kernel<<<NB * NK, NC, 0, stream>>>(f, idx, out_feat);
}

// Round 5
// 60.671 us; speedup vs baseline: 2.3012x; 1.1280x over previous
//
#include <hip/hip_runtime.h>

#define NB 16
#define NC 256
#define NH 56
#define NW 56
#define NHW (NH * NW)          // 3136
#define NK 256
#define TK_THREADS 512
#define CAP 1024

#define QPB 8                  // quads per block
#define NSL 32                 // channel slices (NC/NSL = 8 channels each)
#define CPS (NC / NSL)         // 8
#define NQUAD (NB * NH * (NW / 4))   // 12544 quads
#define P1_BLOCKS (NQUAD / QPB)      // 1568

// ---- sortable-float helpers -------------------------------------------------
__device__ inline unsigned int flip_f32(float f) {
    unsigned int u = __float_as_uint(f);
    return (u & 0x80000000u) ? ~u : (u | 0x80000000u);
}
__device__ inline float unflip_f32(unsigned int u) {
    u = (u & 0x80000000u) ? (u ^ 0x80000000u) : ~u;
    return __uint_as_float(u);
}

// ---- kernel 1: per-pixel norm2 / hprod / vprod maps -------------------------
// Thread = (quad of 4 pixels) x (8-channel slice). Loads are issued in batches
// of 4 channels (20 loads: 12 float4-streams + 8 scalars) into named registers
// BEFORE any FMA consumes them -> ~20 outstanding loads/thread (the round-2..4
// plateau was MLP~1-2: compiler minimized VGPRs and serialized the streams).
__global__ void __launch_bounds__(256)
pass1_kernel(const float* __restrict__ f, float* __restrict__ nmap,
             float* __restrict__ hmap, float* __restrict__ vmap) {
    __shared__ float red[NSL][QPB][12];
    int bid = blockIdx.x;
    int sbid = (bid & 7) * (P1_BLOCKS / 8) + (bid >> 3);   // XCD-chunked
    int tid = threadIdx.x;
    int ql = tid & (QPB - 1);          // local quad
    int sl = tid >> 3;                 // slice 0..31
    int gq = sbid * QPB + ql;          // global quad
    int rowi = gq / 14;                // b*NH + y
    int qx = gq - rowi * 14;
    int b = rowi / NH, y = rowi - b * NH;
    int x0 = qx * 4;

    const float* base = f + (size_t)b * NC * NHW + (size_t)sl * CPS * NHW;
    int xl = (x0 > 0) ? x0 - 1 : 0;
    int xr = (x0 + 4 < NW) ? x0 + 4 : NW - 1;
    int yu = (y < NH - 1) ? y + 1 : NH - 1;
    int yd = (y > 0) ? y - 1 : 0;
    const float* pv = base + y * NW + x0;
    const float* pl = base + y * NW + xl;
    const float* pr = base + y * NW + xr;
    const float* pu = base + yu * NW + x0;
    const float* pd = base + yd * NW + x0;

    float n0 = 0.f, n1 = 0.f, n2 = 0.f, n3 = 0.f;
    float h0 = 0.f, h1 = 0.f, h2 = 0.f, h3 = 0.f;
    float w0 = 0.f, w1 = 0.f, w2 = 0.f, w3 = 0.f;

#pragma unroll
    for (int cc = 0; cc < CPS; cc += 4) {
        float4 V[4], U[4], D[4];
        float L[4], R[4];
#pragma unroll
        for (int c = 0; c < 4; ++c) {          // ---- load phase (20 loads) ----
            size_t off = (size_t)(cc + c) * NHW;
            V[c] = *(const float4*)(pv + off);
            U[c] = *(const float4*)(pu + off);
            D[c] = *(const float4*)(pd + off);
            L[c] = pl[off];
            R[c] = pr[off];
        }
#pragma unroll
        for (int c = 0; c < 4; ++c) {          // ---- compute phase ----
            float4 v = V[c], u = U[c], d = D[c];
            n0 += v.x * v.x; n1 += v.y * v.y; n2 += v.z * v.z; n3 += v.w * v.w;
            h0 += L[c] * v.y; h1 += v.x * v.z; h2 += v.y * v.w; h3 += v.z * R[c];
            w0 += u.x * d.x; w1 += u.y * d.y; w2 += u.z * d.z; w3 += u.w * d.w;
        }
    }
    float* rr = red[sl][ql];
    rr[0] = n0; rr[1] = n1; rr[2]  = n2; rr[3]  = n3;
    rr[4] = h0; rr[5] = h1; rr[6]  = h2; rr[7]  = h3;
    rr[8] = w0; rr[9] = w1; rr[10] = w2; rr[11] = w3;
    __syncthreads();

    if (tid < QPB * 12) {
        int comp = tid >> 3;           // 0..11
        int qi = tid & (QPB - 1);
        float acc = 0.f;
#pragma unroll
        for (int s = 0; s < NSL; ++s) acc += red[s][qi][comp];
        int gq2 = sbid * QPB + qi;
        int rowi2 = gq2 / 14;
        int qx2 = gq2 - rowi2 * 14;
        int j = comp & 3;
        int pix = rowi2 * NW + qx2 * 4 + j;
        float* m = (comp < 4) ? nmap : (comp < 8) ? hmap : vmap;
        m[pix] = acc;
    }
}

// ---- kernel 2: fused sim-finish + per-batch top-K ---------------------------
// sim from nmap/hmap/vmap (nmap staged in LDS); exact radix-select with
// per-wave histograms + wave-parallel suffix scan; ballot-aggregated
// compaction; bitonic sort of <=CAP candidates.
// key = flip(val)<<32 | (0xFFFFFFFF - idx): descending sort == descending
// value, ties -> lower idx first (matches jax.lax.top_k).
__global__ void __launch_bounds__(TK_THREADS)
topk_kernel(const float* __restrict__ nmap, const float* __restrict__ hmap,
            const float* __restrict__ vmap, int* __restrict__ idx_out,
            float* __restrict__ vals_out, float* __restrict__ y_out,
            float* __restrict__ x_out) {
    __shared__ float nsh[NHW];
    __shared__ unsigned int svals[NHW];          // flipped sim values
    __shared__ unsigned int hist8[8][256];       // per-wave histograms
    __shared__ unsigned long long cand[CAP];
    __shared__ unsigned int sh_prefix, sh_mask;
    __shared__ int sh_cnt, sh_above, sh_setS, sh_done;

    const int b = blockIdx.x;
    const int tid = threadIdx.x;
    const int lane = tid & 63;
    const int wv = tid >> 6;
    const float* nb = nmap + (size_t)b * NHW;
    const float* hb = hmap + (size_t)b * NHW;
    const float* vb = vmap + (size_t)b * NHW;

    for (int i = tid; i < NHW; i += TK_THREADS) nsh[i] = nb[i];
    if (tid == 0) { sh_prefix = 0u; sh_mask = 0u; sh_above = 0; sh_done = 0; }
    __syncthreads();

    for (int i = tid; i < NHW; i += TK_THREADS) {
        int y = i / NW, x = i - y * NW;
        int xl = (x > 0) ? x - 1 : 0;
        int xr = (x < NW - 1) ? x + 1 : NW - 1;
        int yu = (y < NH - 1) ? y + 1 : NH - 1;
        int yd = (y > 0) ? y - 1 : 0;
        float h = hb[i], v = vb[i];
        float s = 0.5f * (h / (sqrtf(nsh[y * NW + xl]) * sqrtf(nsh[y * NW + xr])) +
                          v / (sqrtf(nsh[yu * NW + x]) * sqrtf(nsh[yd * NW + x])));
        svals[i] = flip_f32(s);
    }

    // progressive 8-bit radix-select: exact threshold prefix T with
    // #{v >= T} in [NK, 512] (or full 32-bit refinement on heavy ties)
    int shift = 24;
    for (int stage = 0; stage < 4; ++stage) {
        __syncthreads();
        if (sh_done) break;
        for (int i = tid; i < 8 * 256; i += TK_THREADS) ((unsigned int*)hist8)[i] = 0u;
        __syncthreads();
        unsigned int pfx = sh_prefix, msk = sh_mask;
        for (int i = tid; i < NHW; i += TK_THREADS) {
            unsigned int v = svals[i];
            if ((v & msk) == pfx) atomicAdd(&hist8[wv][(v >> shift) & 255u], 1u);
        }
        __syncthreads();
        if (tid < 64) {                 // wave 0: parallel suffix-scan + pick
            int l = tid;
            unsigned int kneed = (unsigned int)(NK - sh_above);
            unsigned int h0 = 0, h1 = 0, h2 = 0, h3 = 0;
#pragma unroll
            for (int w = 0; w < 8; ++w) {
                h0 += hist8[w][4 * l + 0]; h1 += hist8[w][4 * l + 1];
                h2 += hist8[w][4 * l + 2]; h3 += hist8[w][4 * l + 3];
            }
            unsigned int lsum = h0 + h1 + h2 + h3;
            unsigned int s = lsum;
#pragma unroll
            for (int d = 1; d < 64; d <<= 1) {
                unsigned int t = __shfl_down(s, d);
                s += (l + d < 64) ? t : 0u;
            }
            unsigned int above_l = s - lsum;      // digits in lanes > l
            unsigned int suf3 = above_l + h3;
            unsigned int suf2 = suf3 + h2;
            unsigned int suf1 = suf2 + h1;
            unsigned int suf0 = suf1 + h0;
            bool has = (suf0 >= kneed);
            unsigned long long bal = __ballot(has);
            int hl = 63 - __clzll(bal);           // highest lane with a hit
            if (l == hl) {
                int c; unsigned int above, hc;
                if (suf3 >= kneed)      { c = 4 * l + 3; above = above_l; hc = h3; }
                else if (suf2 >= kneed) { c = 4 * l + 2; above = suf3;    hc = h2; }
                else if (suf1 >= kneed) { c = 4 * l + 1; above = suf2;    hc = h1; }
                else                    { c = 4 * l + 0; above = suf1;    hc = h0; }
                sh_above += (int)above;
                sh_setS = (int)hc;
                sh_prefix |= ((unsigned int)c) << shift;
                sh_mask   |= 255u << shift;
                if (sh_above + sh_setS <= 512 || shift == 0) sh_done = 1;
            }
        }
        shift -= 8;
    }
    __syncthreads();

    // ballot-aggregated compaction of candidates v >= T
    if (tid == 0) sh_cnt = 0;
    __syncthreads();
    unsigned int T = sh_prefix;
    for (int i = tid; i < NHW; i += TK_THREADS) {
        unsigned int v = svals[i];
        bool keep = (v >= T);
        unsigned long long m = __ballot(keep);
        int basep = 0;
        if (lane == 0) basep = atomicAdd(&sh_cnt, __popcll(m));
        basep = __shfl(basep, 0);
        if (keep) {
            int pos = basep + __popcll(m & ((1ull << lane) - 1ull));
            if (pos < CAP)
                cand[pos] = ((unsigned long long)v << 32) |
                            (unsigned long long)(0xFFFFFFFFu - (unsigned int)i);
        }
    }
    __syncthreads();
    int nc = sh_cnt; if (nc > CAP) nc = CAP;
    const int NS = (nc <= 512) ? 512 : CAP;
    for (int i = tid; i < NS; i += TK_THREADS) if (i >= nc) cand[i] = 0ull;
    __syncthreads();

    // bitonic sort NS keys descending
    for (int k = 2; k <= NS; k <<= 1) {
        for (int j = k >> 1; j > 0; j >>= 1) {
            for (int i = tid; i < NS; i += TK_THREADS) {
                int ixj = i ^ j;
                if (ixj > i) {
                    unsigned long long a = cand[i], c2 = cand[ixj];
                    bool sw = ((i & k) == 0) ? (a < c2) : (a > c2);
                    if (sw) { cand[i] = c2; cand[ixj] = a; }
                }
            }
            __syncthreads();
        }
    }

    if (tid < NK) {
        unsigned long long kk = cand[tid];
        unsigned int lo = (unsigned int)(kk & 0xFFFFFFFFull);
        int idx = (int)(0xFFFFFFFFu - lo);
        float val = unflip_f32((unsigned int)(kk >> 32));
        int o = b * NK + tid;
        idx_out[o] = idx;
        vals_out[o] = val;
        y_out[o] = (float)(idx / NW);
        x_out[o] = (float)(idx % NW);
    }
}

// ---- kernel 3: gather point features [B,K,C] --------------------------------
__global__ void gather_kernel(const float* __restrict__ f, const int* __restrict__ idx,
                              float* __restrict__ out) {
    int blk = blockIdx.x;          // b*NK + k
    int b = blk >> 8;              // NK == 256
    int p = idx[blk];
    out[(size_t)blk * NC + threadIdx.x] =
        f[(size_t)b * NC * NHW + (size_t)threadIdx.x * NHW + (size_t)p];
}

extern "C" void kernel_launch(void* const* d_in, const int* in_sizes, int n_in,
                              void* d_out, int out_size, void* d_ws, size_t ws_size,
                              hipStream_t stream) {
    const float* f = (const float*)d_in[0];

    // output layout: point_feat [B,K,C] | vals [B,K] | ycoord [B,K] | xcoord [B,K]
    float* out_feat = (float*)d_out;
    float* out_vals = out_feat + (size_t)NB * NK * NC;
    float* out_y    = out_vals + (size_t)NB * NK;
    float* out_x    = out_y    + (size_t)NB * NK;

    // workspace: nmap | hmap | vmap (each B*HW f32) | idx (B*K i32)
    float* nmap = (float*)d_ws;
    float* hmap = nmap + (size_t)NB * NHW;
    float* vmap = hmap + (size_t)NB * NHW;
    int*   idx  = (int*)(vmap + (size_t)NB * NHW);

    pass1_kernel<<<P1_BLOCKS, 256, 0, stream>>>(f, nmap, hmap, vmap);
    topk_kernel<<<NB, TK_THREADS, 0, stream>>>(nmap, hmap, vmap, idx,
                                               out_vals, out_y, out_x);
    gather_kernel<<<NB * NK, NC, 0, stream>>>(f, idx, out_feat);
}

// Round 6
// 53.363 us; speedup vs baseline: 2.6163x; 1.1369x over previous
//
#include <hip/hip_runtime.h>

#define NB 16
#define NC 256
#define NH 56
#define NW 56
#define NHW (NH * NW)          // 3136
#define NK 256
#define TK_THREADS 1024
#define CAP 1024

#define CS 16                  // channels per staged chunk
#define RS 4                   // rows staged (2 compute + 2 halo)
#define NCHUNK (NC / CS)       // 16
#define CHUNK16 (CS * RS * NW * 4 / 16)   // 896 16B-chunks per stage
#define P1_BLOCKS (NB * (NH / 2))         // 448

// ---- sortable-float helpers -------------------------------------------------
__device__ inline unsigned int flip_f32(float f) {
    unsigned int u = __float_as_uint(f);
    return (u & 0x80000000u) ? ~u : (u | 0x80000000u);
}
__device__ inline float unflip_f32(unsigned int u) {
    u = (u & 0x80000000u) ? (u ^ 0x80000000u) : ~u;
    return __uint_as_float(u);
}

// ---- kernel 1: per-pixel norm2 / hprod / vprod maps -------------------------
// Block = (batch, band of 2 rows) x ALL 256 channels (16-ch chunks, LDS
// double-buffered via global_load_lds -> linear dest, contiguous 896B-per-
// channel source runs, zero VGPR staging). Compute reads b128 quads from LDS.
// All channels reduced in-block in fixed order -> deterministic, no atomics.
__global__ void __launch_bounds__(256)
pass1_kernel(const float* __restrict__ f, float* __restrict__ nmap,
             float* __restrict__ hmap, float* __restrict__ vmap) {
    __shared__ float buf[2][CS * RS * NW];     // 2 x 14336 B
    __shared__ float redbuf[28][8][12];        // 10.5 KB

    int bid = blockIdx.x;
    int sb = (bid & 7) * (P1_BLOCKS / 8) + (bid >> 3);   // XCD-chunked
    int b = sb / 28, band = sb - b * 28;
    int y0 = band * 2;
    int tid = threadIdx.x;
    const float* fb = f + (size_t)b * NC * NHW;

    auto stage = [&](int ci, float* dst) {
        int c0 = ci * CS;
#pragma unroll
        for (int i = 0; i < 4; ++i) {
            int k = tid + 256 * i;
            if (k < CHUNK16) {
                int ch = k / 56;               // 56 16B-chunks per channel
                int rem = k - ch * 56;
                int rl = rem / 14;             // staged row 0..3
                int xk = rem - rl * 14;        // 16B chunk within row
                int rg = y0 - 1 + rl;
                rg = rg < 0 ? 0 : (rg > NH - 1 ? NH - 1 : rg);
                const float* src = fb + (size_t)(c0 + ch) * NHW + rg * NW + xk * 4;
                __builtin_amdgcn_global_load_lds(
                    (const __attribute__((address_space(1))) void*)src,
                    (__attribute__((address_space(3))) void*)(dst + k * 4),
                    16, 0, 0);
            }
        }
    };

    // compute-thread geometry: tid<224 -> quad (2 rows x 14 quads) x chgroup(8)
    int quad = tid % 28;
    int chg = tid / 28;
    int r = quad / 14, qx = quad - r * 14, x0 = qx * 4;
    int xl = x0 ? x0 - 1 : 0;
    int xr = (x0 + 4 < NW) ? x0 + 4 : NW - 1;

    float n0 = 0.f, n1 = 0.f, n2 = 0.f, n3 = 0.f;
    float h0 = 0.f, h1 = 0.f, h2 = 0.f, h3 = 0.f;
    float w0 = 0.f, w1 = 0.f, w2 = 0.f, w3 = 0.f;

    stage(0, buf[0]);
    __syncthreads();                            // drains staging (vmcnt)
    for (int ci = 0; ci < NCHUNK; ++ci) {
        if (ci + 1 < NCHUNK) stage(ci + 1, buf[(ci + 1) & 1]);
        if (tid < 224) {
            const float* sbf = buf[ci & 1];
#pragma unroll
            for (int c = 0; c < 2; ++c) {
                const float* Bm = sbf + (chg * 2 + c) * (RS * NW) + (r + 1) * NW;
                float4 v = *(const float4*)(Bm + x0);
                float  l = Bm[xl];
                float  rr = Bm[xr];
                float4 u = *(const float4*)(Bm + NW + x0);   // global y+1
                float4 d = *(const float4*)(Bm - NW + x0);   // global y-1
                n0 += v.x * v.x; n1 += v.y * v.y; n2 += v.z * v.z; n3 += v.w * v.w;
                h0 += l * v.y;   h1 += v.x * v.z; h2 += v.y * v.w; h3 += v.z * rr;
                w0 += u.x * d.x; w1 += u.y * d.y; w2 += u.z * d.z; w3 += u.w * d.w;
            }
        }
        __syncthreads();   // compute done + next stage landed
    }

    if (tid < 224) {
        float* rb = redbuf[quad][chg];
        rb[0] = n0; rb[1] = n1; rb[2]  = n2; rb[3]  = n3;
        rb[4] = h0; rb[5] = h1; rb[6]  = h2; rb[7]  = h3;
        rb[8] = w0; rb[9] = w1; rb[10] = w2; rb[11] = w3;
    }
    __syncthreads();

    for (int oi = tid; oi < 28 * 12; oi += 256) {
        int q = oi / 12, comp = oi - q * 12;
        float acc = 0.f;
#pragma unroll
        for (int g = 0; g < 8; ++g) acc += redbuf[q][g][comp];
        int r2 = q / 14, qx2 = q - r2 * 14;
        int j = comp & 3;
        float* m = (comp < 4) ? nmap : (comp < 8) ? hmap : vmap;
        m[((size_t)b * NH + y0 + r2) * NW + qx2 * 4 + j] = acc;
    }
}

// ---- kernel 2: fused sim-finish + per-batch top-K ---------------------------
// sim from nmap/hmap/vmap (nmap staged in LDS); exact radix-select with
// per-wave histograms + wave-parallel suffix scan; ballot-aggregated
// compaction; bitonic sort of <=CAP candidates.
// key = flip(val)<<32 | (0xFFFFFFFF - idx): descending sort == descending
// value, ties -> lower idx first (matches jax.lax.top_k).
__global__ void __launch_bounds__(TK_THREADS)
topk_kernel(const float* __restrict__ nmap, const float* __restrict__ hmap,
            const float* __restrict__ vmap, int* __restrict__ idx_out,
            float* __restrict__ vals_out, float* __restrict__ y_out,
            float* __restrict__ x_out) {
    __shared__ float nsh[NHW];
    __shared__ unsigned int svals[NHW];          // flipped sim values
    __shared__ unsigned int hist16[16][256];     // per-wave histograms
    __shared__ unsigned long long cand[CAP];
    __shared__ unsigned int sh_prefix, sh_mask;
    __shared__ int sh_cnt, sh_above, sh_setS, sh_done;

    const int b = blockIdx.x;
    const int tid = threadIdx.x;
    const int lane = tid & 63;
    const int wv = tid >> 6;
    const float* nb = nmap + (size_t)b * NHW;
    const float* hb = hmap + (size_t)b * NHW;
    const float* vb = vmap + (size_t)b * NHW;

    for (int i = tid; i < NHW; i += TK_THREADS) nsh[i] = nb[i];
    if (tid == 0) { sh_prefix = 0u; sh_mask = 0u; sh_above = 0; sh_done = 0; }
    __syncthreads();

    for (int i = tid; i < NHW; i += TK_THREADS) {
        int y = i / NW, x = i - y * NW;
        int xl = (x > 0) ? x - 1 : 0;
        int xr = (x < NW - 1) ? x + 1 : NW - 1;
        int yu = (y < NH - 1) ? y + 1 : NH - 1;
        int yd = (y > 0) ? y - 1 : 0;
        float h = hb[i], v = vb[i];
        float s = 0.5f * (h / (sqrtf(nsh[y * NW + xl]) * sqrtf(nsh[y * NW + xr])) +
                          v / (sqrtf(nsh[yu * NW + x]) * sqrtf(nsh[yd * NW + x])));
        svals[i] = flip_f32(s);
    }

    // progressive 8-bit radix-select: exact threshold prefix T with
    // #{v >= T} in [NK, 512] (or full 32-bit refinement on heavy ties)
    int shift = 24;
    for (int stage = 0; stage < 4; ++stage) {
        __syncthreads();
        if (sh_done) break;
        for (int i = tid; i < 16 * 256; i += TK_THREADS) ((unsigned int*)hist16)[i] = 0u;
        __syncthreads();
        unsigned int pfx = sh_prefix, msk = sh_mask;
        for (int i = tid; i < NHW; i += TK_THREADS) {
            unsigned int v = svals[i];
            if ((v & msk) == pfx) atomicAdd(&hist16[wv][(v >> shift) & 255u], 1u);
        }
        __syncthreads();
        if (tid < 64) {                 // wave 0: parallel suffix-scan + pick
            int l = tid;
            unsigned int kneed = (unsigned int)(NK - sh_above);
            unsigned int h0 = 0, h1 = 0, h2 = 0, h3 = 0;
#pragma unroll
            for (int w = 0; w < 16; ++w) {
                h0 += hist16[w][4 * l + 0]; h1 += hist16[w][4 * l + 1];
                h2 += hist16[w][4 * l + 2]; h3 += hist16[w][4 * l + 3];
            }
            unsigned int lsum = h0 + h1 + h2 + h3;
            unsigned int s = lsum;
#pragma unroll
            for (int d = 1; d < 64; d <<= 1) {
                unsigned int t = __shfl_down(s, d);
                s += (l + d < 64) ? t : 0u;
            }
            unsigned int above_l = s - lsum;      // digits in lanes > l
            unsigned int suf3 = above_l + h3;
            unsigned int suf2 = suf3 + h2;
            unsigned int suf1 = suf2 + h1;
            unsigned int suf0 = suf1 + h0;
            bool has = (suf0 >= kneed);
            unsigned long long bal = __ballot(has);
            int hl = 63 - __clzll(bal);           // highest lane with a hit
            if (l == hl) {
                int c; unsigned int above, hc;
                if (suf3 >= kneed)      { c = 4 * l + 3; above = above_l; hc = h3; }
                else if (suf2 >= kneed) { c = 4 * l + 2; above = suf3;    hc = h2; }
                else if (suf1 >= kneed) { c = 4 * l + 1; above = suf2;    hc = h1; }
                else                    { c = 4 * l + 0; above = suf1;    hc = h0; }
                sh_above += (int)above;
                sh_setS = (int)hc;
                sh_prefix |= ((unsigned int)c) << shift;
                sh_mask   |= 255u << shift;
                if (sh_above + sh_setS <= 512 || shift == 0) sh_done = 1;
            }
        }
        shift -= 8;
    }
    __syncthreads();

    // ballot-aggregated compaction of candidates v >= T
    if (tid == 0) sh_cnt = 0;
    __syncthreads();
    unsigned int T = sh_prefix;
    for (int i = tid; i < NHW; i += TK_THREADS) {
        unsigned int v = svals[i];
        bool keep = (v >= T);
        unsigned long long m = __ballot(keep);
        int basep = 0;
        if (lane == 0) basep = atomicAdd(&sh_cnt, __popcll(m));
        basep = __shfl(basep, 0);
        if (keep) {
            int pos = basep + __popcll(m & ((1ull << lane) - 1ull));
            if (pos < CAP)
                cand[pos] = ((unsigned long long)v << 32) |
                            (unsigned long long)(0xFFFFFFFFu - (unsigned int)i);
        }
    }
    __syncthreads();
    int nc = sh_cnt; if (nc > CAP) nc = CAP;
    const int NS = (nc <= 512) ? 512 : CAP;
    for (int i = tid; i < NS; i += TK_THREADS) if (i >= nc) cand[i] = 0ull;
    __syncthreads();

    // bitonic sort NS keys descending
    for (int k = 2; k <= NS; k <<= 1) {
        for (int j = k >> 1; j > 0; j >>= 1) {
            for (int i = tid; i < NS; i += TK_THREADS) {
                int ixj = i ^ j;
                if (ixj > i) {
                    unsigned long long a = cand[i], c2 = cand[ixj];
                    bool sw = ((i & k) == 0) ? (a < c2) : (a > c2);
                    if (sw) { cand[i] = c2; cand[ixj] = a; }
                }
            }
            __syncthreads();
        }
    }

    if (tid < NK) {
        unsigned long long kk = cand[tid];
        unsigned int lo = (unsigned int)(kk & 0xFFFFFFFFull);
        int idx = (int)(0xFFFFFFFFu - lo);
        float val = unflip_f32((unsigned int)(kk >> 32));
        int o = b * NK + tid;
        idx_out[o] = idx;
        vals_out[o] = val;
        y_out[o] = (float)(idx / NW);
        x_out[o] = (float)(idx % NW);
    }
}

// ---- kernel 3: gather point features [B,K,C] --------------------------------
__global__ void gather_kernel(const float* __restrict__ f, const int* __restrict__ idx,
                              float* __restrict__ out) {
    int blk = blockIdx.x;          // b*NK + k
    int b = blk >> 8;              // NK == 256
    int p = idx[blk];
    out[(size_t)blk * NC + threadIdx.x] =
        f[(size_t)b * NC * NHW + (size_t)threadIdx.x * NHW + (size_t)p];
}

extern "C" void kernel_launch(void* const* d_in, const int* in_sizes, int n_in,
                              void* d_out, int out_size, void* d_ws, size_t ws_size,
                              hipStream_t stream) {
    const float* f = (const float*)d_in[0];

    // output layout: point_feat [B,K,C] | vals [B,K] | ycoord [B,K] | xcoord [B,K]
    float* out_feat = (float*)d_out;
    float* out_vals = out_feat + (size_t)NB * NK * NC;
    float* out_y    = out_vals + (size_t)NB * NK;
    float* out_x    = out_y    + (size_t)NB * NK;

    // workspace: nmap | hmap | vmap (each B*HW f32) | idx (B*K i32)
    float* nmap = (float*)d_ws;
    float* hmap = nmap + (size_t)NB * NHW;
    float* vmap = hmap + (size_t)NB * NHW;
    int*   idx  = (int*)(vmap + (size_t)NB * NHW);

    pass1_kernel<<<P1_BLOCKS, 256, 0, stream>>>(f, nmap, hmap, vmap);
    topk_kernel<<<NB, TK_THREADS, 0, stream>>>(nmap, hmap, vmap, idx,
                                               out_vals, out_y, out_x);
    gather_kernel<<<NB * NK, NC, 0, stream>>>(f, idx, out_feat);
}